// Round 1
// 4143.850 us; speedup vs baseline: 1.8739x; 1.8739x over previous
//
#include <hip/hip_runtime.h>

using u16 = unsigned short;

constexpr int CIN = 16, COUT = 32, COFF = 16;
constexpr int D = 32, H = 128, W = 160;
constexpr int HW = H * W;         // 20480
constexpr int DHW = D * HW;       // 655360
constexpr int NOUT = COUT * DHW;  // 20971520
constexpr float EPS = 1e-5f;

// ---- workspace layout (byte offsets) ----
constexpr size_t WF_OFF = 16384;
constexpr size_t A1_OFF = 262144;
constexpr size_t OUT2_OFF = 50331648;  // 48 MiB: conv outputs (a,b) live here when ws permits
constexpr int WOFF_O = 0, WREG_O = 2592, W2_O = 7200, WD_O = 34848;
constexpr int G1_O = 48672, B1_O = 48704, G2_O = 48736, B2_O = 48768, GD_O = 48800, BD_O = 48832;
constexpr int FLAG_SLOT = 3000;

static __device__ __forceinline__ float bf2f(u16 h) {
  unsigned u = ((unsigned)h) << 16;
  float f;
  __builtin_memcpy(&f, &u, 4);
  return f;
}
static __device__ __forceinline__ u16 f2bf(float f) {
  unsigned u;
  __builtin_memcpy(&u, &f, 4);
  u += 0x7fffu + ((u >> 16) & 1u);
  return (u16)(u >> 16);
}
static __device__ __forceinline__ float ldin(const void* p, int i, int bf) {
  float r;
  if (bf) r = bf2f(((const u16*)p)[i]);
  else r = ((const float*)p)[i];
  return r;
}

__global__ __launch_bounds__(256) void zero_kernel(float* __restrict__ S) {
  S[blockIdx.x * 256 + threadIdx.x] = 0.f;
}

__global__ __launch_bounds__(256) void sniff_kernel(const u16* __restrict__ x,
                                                    int* __restrict__ flag) {
  __shared__ int sh[256];
  int cnt = 0;
  for (int i = threadIdx.x; i < 4096; i += 256) {
    int e = (x[i] >> 7) & 0xff;
    cnt += (e >= 96 && e <= 144) ? 1 : 0;
  }
  sh[threadIdx.x] = cnt;
  __syncthreads();
  for (int s = 128; s > 0; s >>= 1) {
    if (threadIdx.x < (unsigned)s) sh[threadIdx.x] += sh[threadIdx.x + s];
    __syncthreads();
  }
  if (threadIdx.x == 0) flag[0] = (sh[0] > 3072) ? 1 : 0;
}

__global__ __launch_bounds__(256) void cvt_kernel(const void* __restrict__ in,
                                                  float* __restrict__ out, int n,
                                                  const int* __restrict__ flagp) {
  int bf = flagp[0];
  int i = blockIdx.x * 256 + threadIdx.x;
  if (i < n) out[i] = ldin(in, i, bf);
}

// Deformable conv: one thread per (d, y, x).  (verbatim from the passing build)
__global__ __launch_bounds__(256) void deform_kernel(const void* __restrict__ x,
                                                     const void* __restrict__ f,
                                                     const float* __restrict__ w_off_f,
                                                     const float* __restrict__ w_reg_f,
                                                     u16* __restrict__ a1,
                                                     const int* __restrict__ flagp) {
  const int bf = flagp[0];
  const int bid = blockIdx.x;
  const int d = bid / (HW / 256);
  const int p = (bid % (HW / 256)) * 256 + threadIdx.x;
  const int y = p / W;
  const int xx = p % W;

  float doff[18];
#pragma unroll
  for (int t = 0; t < 18; t++) doff[t] = 0.f;
  for (int ci = 0; ci < COFF; ci++) {
    const int fbase = ci * DHW + d * HW;
#pragma unroll
    for (int ki = 0; ki < 3; ki++) {
      int yy = y - 1 + ki;
      bool yok = (unsigned)yy < (unsigned)H;
#pragma unroll
      for (int kj = 0; kj < 3; kj++) {
        int xj = xx - 1 + kj;
        float v = (yok && (unsigned)xj < (unsigned)W) ? ldin(f, fbase + yy * W + xj, bf) : 0.f;
        int widx = ci * 9 + ki * 3 + kj;
#pragma unroll
        for (int t = 0; t < 18; t++) doff[t] += v * w_off_f[t * 144 + widx];
      }
    }
  }

  float acc[COUT];
#pragma unroll
  for (int co = 0; co < COUT; co++) acc[co] = 0.f;

#pragma unroll
  for (int t = 0; t < 9; t++) {
    float dy = fminf(fmaxf(doff[2 * t], -1.f), 1.f);
    float dx = fminf(fmaxf(doff[2 * t + 1], -1.f), 1.f);
    float py = (float)(y - 1 + t / 3) + dy;
    float px = (float)(xx - 1 + t % 3) + dx;
    float y0f = floorf(py), x0f = floorf(px);
    float wy1 = py - y0f, wx1 = px - x0f;
    int y0 = (int)y0f, x0i = (int)x0f;
    int y1 = y0 + 1, x1 = x0i + 1;
    bool y0v = (unsigned)y0 < (unsigned)H, y1v = (unsigned)y1 < (unsigned)H;
    bool x0v = (unsigned)x0i < (unsigned)W, x1v = (unsigned)x1 < (unsigned)W;
    float c00 = (y0v && x0v) ? (1.f - wy1) * (1.f - wx1) : 0.f;
    float c01 = (y0v && x1v) ? (1.f - wy1) * wx1 : 0.f;
    float c10 = (y1v && x0v) ? wy1 * (1.f - wx1) : 0.f;
    float c11 = (y1v && x1v) ? wy1 * wx1 : 0.f;
    int y0c = min(max(y0, 0), H - 1) * W, y1c = min(max(y1, 0), H - 1) * W;
    int x0c = min(max(x0i, 0), W - 1), x1c = min(max(x1, 0), W - 1);

    for (int ci = 0; ci < CIN; ci++) {
      const int xbase = ci * DHW + d * HW;
      float s = c00 * ldin(x, xbase + y0c + x0c, bf) + c01 * ldin(x, xbase + y0c + x1c, bf) +
                c10 * ldin(x, xbase + y1c + x0c, bf) + c11 * ldin(x, xbase + y1c + x1c, bf);
#pragma unroll
      for (int co = 0; co < COUT; co++) acc[co] += s * w_reg_f[co * 144 + ci * 9 + t];
    }
  }

#pragma unroll
  for (int co = 0; co < COUT; co++) a1[co * DHW + d * HW + p] = f2bf(acc[co]);
}

__global__ __launch_bounds__(256) void bn1_stats_kernel(const u16* __restrict__ a1,
                                                        const float* __restrict__ g1f,
                                                        const float* __restrict__ b1f,
                                                        float* __restrict__ S) {
  int cd = blockIdx.x;
  int c = cd / D;
  const u16* p = a1 + (size_t)cd * HW;
  float sum = 0.f, sq = 0.f;
  for (int i = threadIdx.x; i < HW; i += 256) {
    float v = bf2f(p[i]);
    sum += v;
    sq += v * v;
  }
  __shared__ float sh[512];
  sh[threadIdx.x] = sum;
  sh[256 + threadIdx.x] = sq;
  __syncthreads();
  for (int s = 128; s > 0; s >>= 1) {
    if (threadIdx.x < (unsigned)s) {
      sh[threadIdx.x] += sh[threadIdx.x + s];
      sh[256 + threadIdx.x] += sh[256 + threadIdx.x + s];
    }
    __syncthreads();
  }
  if (threadIdx.x == 0) {
    float mean = sh[0] / (float)HW;
    float var = sh[256] / (float)HW - mean * mean;
    float sc = g1f[c] * rsqrtf(var + EPS);
    S[cd] = sc;
    S[1024 + cd] = b1f[c] - mean * sc;
  }
}

__global__ __launch_bounds__(256) void bn1_apply_kernel(u16* __restrict__ a1,
                                                        const float* __restrict__ S) {
  int i = (blockIdx.x * 256 + threadIdx.x) * 4;
  int cd = i / HW;
  float sc = S[cd], of = S[1024 + cd];
  ushort4 v = *(const ushort4*)(a1 + i);
  ushort4 r;
  r.x = f2bf(fmaxf(bf2f(v.x) * sc + of, 0.f));
  r.y = f2bf(fmaxf(bf2f(v.y) * sc + of, 0.f));
  r.z = f2bf(fmaxf(bf2f(v.z) * sc + of, 0.f));
  r.w = f2bf(fmaxf(bf2f(v.w) * sc + of, 0.f));
  *(ushort4*)(a1 + i) = r;
}

// -------- store-once path: compute BOTH convs once, store raw outputs + stats --------
// Body identical to the proven final_conv_kernel conv loops; instead of applying BN
// (scales unknown yet) it stores a/b and accumulates per-channel sum/sumsq.
__global__ __launch_bounds__(256) void conv_store_kernel(const u16* __restrict__ a1,
                                                         const void* __restrict__ x,
                                                         const float* __restrict__ w2f,
                                                         const float* __restrict__ wdf,
                                                         const int* __restrict__ flagp, int st32,
                                                         void* __restrict__ out2,
                                                         void* __restrict__ outd,
                                                         float* __restrict__ S) {
  const int bf = flagp[0];
  const int bid = blockIdx.x;
  const int co = bid & 31;
  const int rem = bid >> 5;
  const int d = rem / 20;
  const int p = (rem % 20) * 256 + threadIdx.x;
  const int y = p / 40;
  const int x0 = (p % 40) * 4;

  float a0 = 0.f, a1v = 0.f, a2 = 0.f, a3 = 0.f;  // main conv (from a1, 32 ci)
  for (int ci = 0; ci < COUT; ci++) {
#pragma unroll
    for (int kd = 0; kd < 3; kd++) {
      int dd = d - 1 + kd;
      if ((unsigned)dd >= (unsigned)D) continue;
      const int base = ci * DHW + dd * HW;
#pragma unroll
      for (int ky = 0; ky < 3; ky++) {
        int yy = y - 1 + ky;
        if ((unsigned)yy >= (unsigned)H) continue;
        const u16* row = a1 + base + yy * W;
        float r[6];
        {
          ushort4 v4 = *(const ushort4*)(row + x0);
          r[1] = bf2f(v4.x); r[2] = bf2f(v4.y); r[3] = bf2f(v4.z); r[4] = bf2f(v4.w);
        }
        r[0] = (x0 > 0) ? bf2f(row[x0 - 1]) : 0.f;
        r[5] = (x0 + 4 < W) ? bf2f(row[x0 + 4]) : 0.f;
        const float* wp = w2f + (((co * COUT + ci) * 3 + kd) * 3 + ky) * 3;
        float w0 = wp[0], w1 = wp[1], w2 = wp[2];
        a0 += r[0] * w0 + r[1] * w1 + r[2] * w2;
        a1v += r[1] * w0 + r[2] * w1 + r[3] * w2;
        a2 += r[2] * w0 + r[3] * w1 + r[4] * w2;
        a3 += r[3] * w0 + r[4] * w1 + r[5] * w2;
      }
    }
  }
  float b0 = 0.f, b1v = 0.f, b2v = 0.f, b3 = 0.f;  // identity conv (from x, 16 ci)
  for (int ci = 0; ci < CIN; ci++) {
#pragma unroll
    for (int kd = 0; kd < 3; kd++) {
      int dd = d - 1 + kd;
      if ((unsigned)dd >= (unsigned)D) continue;
      const int base = ci * DHW + dd * HW;
#pragma unroll
      for (int ky = 0; ky < 3; ky++) {
        int yy = y - 1 + ky;
        if ((unsigned)yy >= (unsigned)H) continue;
        const int rbase = base + yy * W;
        float r[6];
        if (bf) {
          ushort4 v4 = *(const ushort4*)((const u16*)x + rbase + x0);
          r[1] = bf2f(v4.x); r[2] = bf2f(v4.y); r[3] = bf2f(v4.z); r[4] = bf2f(v4.w);
        } else {
          float4 v4 = *(const float4*)((const float*)x + rbase + x0);
          r[1] = v4.x; r[2] = v4.y; r[3] = v4.z; r[4] = v4.w;
        }
        r[0] = (x0 > 0) ? ldin(x, rbase + x0 - 1, bf) : 0.f;
        r[5] = (x0 + 4 < W) ? ldin(x, rbase + x0 + 4, bf) : 0.f;
        const float* wp = wdf + (((co * CIN + ci) * 3 + kd) * 3 + ky) * 3;
        float w0 = wp[0], w1 = wp[1], w2 = wp[2];
        b0 += r[0] * w0 + r[1] * w1 + r[2] * w2;
        b1v += r[1] * w0 + r[2] * w1 + r[3] * w2;
        b2v += r[2] * w0 + r[3] * w1 + r[4] * w2;
        b3 += r[3] * w0 + r[4] * w1 + r[5] * w2;
      }
    }
  }

  const int oi = co * DHW + d * HW + y * W + x0;
  if (st32) {
    float4 va; va.x = a0; va.y = a1v; va.z = a2; va.w = a3;
    *(float4*)((float*)out2 + oi) = va;
    float4 vb; vb.x = b0; vb.y = b1v; vb.z = b2v; vb.w = b3;
    *(float4*)((float*)outd + oi) = vb;
  } else {
    ushort4 sa; sa.x = f2bf(a0); sa.y = f2bf(a1v); sa.z = f2bf(a2); sa.w = f2bf(a3);
    *(ushort4*)((u16*)out2 + oi) = sa;
    ushort4 sb; sb.x = f2bf(b0); sb.y = f2bf(b1v); sb.z = f2bf(b2v); sb.w = f2bf(b3);
    *(ushort4*)((u16*)outd + oi) = sb;
  }

  float ps = a0 + a1v + a2 + a3;
  float pq = a0 * a0 + a1v * a1v + a2 * a2 + a3 * a3;
  float psb = b0 + b1v + b2v + b3;
  float pqb = b0 * b0 + b1v * b1v + b2v * b2v + b3 * b3;
  __shared__ float sh[1024];
  sh[threadIdx.x] = ps;
  sh[256 + threadIdx.x] = pq;
  sh[512 + threadIdx.x] = psb;
  sh[768 + threadIdx.x] = pqb;
  __syncthreads();
  for (int s = 128; s > 0; s >>= 1) {
    if (threadIdx.x < (unsigned)s) {
      sh[threadIdx.x] += sh[threadIdx.x + s];
      sh[256 + threadIdx.x] += sh[256 + threadIdx.x + s];
      sh[512 + threadIdx.x] += sh[512 + threadIdx.x + s];
      sh[768 + threadIdx.x] += sh[768 + threadIdx.x + s];
    }
    __syncthreads();
  }
  if (threadIdx.x == 0) {
    atomicAdd(&S[2048 + co], sh[0]);
    atomicAdd(&S[2080 + co], sh[256]);
    atomicAdd(&S[2112 + co], sh[512]);
    atomicAdd(&S[2144 + co], sh[768]);
  }
}

// elementwise: out = relu(a*s2+o2 + b*sd+od)
__global__ __launch_bounds__(256) void combine_kernel(const void* __restrict__ out2,
                                                      const void* __restrict__ outd,
                                                      const float* __restrict__ S,
                                                      const int* __restrict__ flagp, int st32,
                                                      void* __restrict__ out) {
  int i = (blockIdx.x * 256 + threadIdx.x) * 4;
  int co = i / DHW;
  float s2 = S[2176 + co], o2 = S[2208 + co];
  float sd = S[2240 + co], od = S[2272 + co];
  float a[4], b[4];
  if (st32) {
    float4 va = *(const float4*)((const float*)out2 + i);
    a[0] = va.x; a[1] = va.y; a[2] = va.z; a[3] = va.w;
    float4 vb = *(const float4*)((const float*)outd + i);
    b[0] = vb.x; b[1] = vb.y; b[2] = vb.z; b[3] = vb.w;
  } else {
    ushort4 va = *(const ushort4*)((const u16*)out2 + i);
    a[0] = bf2f(va.x); a[1] = bf2f(va.y); a[2] = bf2f(va.z); a[3] = bf2f(va.w);
    ushort4 vb = *(const ushort4*)((const u16*)outd + i);
    b[0] = bf2f(vb.x); b[1] = bf2f(vb.y); b[2] = bf2f(vb.z); b[3] = bf2f(vb.w);
  }
  float r[4];
#pragma unroll
  for (int k = 0; k < 4; k++) r[k] = fmaxf(a[k] * s2 + o2 + b[k] * sd + od, 0.f);
  int bf = flagp[0];
  if (bf) {
    ushort4 st;
    st.x = f2bf(r[0]); st.y = f2bf(r[1]); st.z = f2bf(r[2]); st.w = f2bf(r[3]);
    *(ushort4*)((u16*)out + i) = st;
  } else {
    float4 st;
    st.x = r[0]; st.y = r[1]; st.z = r[2]; st.w = r[3];
    *(float4*)((float*)out + i) = st;
  }
}

// -------- fallback path (verbatim from the proven build) --------
__global__ __launch_bounds__(256) void conv_stats_kernel(const void* __restrict__ in,
                                                         const float* __restrict__ wt, int nci,
                                                         int force_bf, const int* __restrict__ flagp,
                                                         float* __restrict__ sum,
                                                         float* __restrict__ sq) {
  const int bf = force_bf ? 1 : flagp[0];
  const int bid = blockIdx.x;
  const int co = bid & 31;
  const int rem = bid >> 5;
  const int d = rem / 20;
  const int p = (rem % 20) * 256 + threadIdx.x;
  const int y = p / 40;
  const int x0 = (p % 40) * 4;

  float a0 = 0.f, a1v = 0.f, a2 = 0.f, a3 = 0.f;
  for (int ci = 0; ci < nci; ci++) {
#pragma unroll
    for (int kd = 0; kd < 3; kd++) {
      int dd = d - 1 + kd;
      if ((unsigned)dd >= (unsigned)D) continue;
      const int base = ci * DHW + dd * HW;
#pragma unroll
      for (int ky = 0; ky < 3; ky++) {
        int yy = y - 1 + ky;
        if ((unsigned)yy >= (unsigned)H) continue;
        const int rbase = base + yy * W;
        float r[6];
        if (bf) {
          ushort4 v4 = *(const ushort4*)((const u16*)in + rbase + x0);
          r[1] = bf2f(v4.x); r[2] = bf2f(v4.y); r[3] = bf2f(v4.z); r[4] = bf2f(v4.w);
        } else {
          float4 v4 = *(const float4*)((const float*)in + rbase + x0);
          r[1] = v4.x; r[2] = v4.y; r[3] = v4.z; r[4] = v4.w;
        }
        r[0] = (x0 > 0) ? ldin(in, rbase + x0 - 1, bf) : 0.f;
        r[5] = (x0 + 4 < W) ? ldin(in, rbase + x0 + 4, bf) : 0.f;
        const float* wp = wt + (((co * nci + ci) * 3 + kd) * 3 + ky) * 3;
        float w0 = wp[0], w1 = wp[1], w2 = wp[2];
        a0 += r[0] * w0 + r[1] * w1 + r[2] * w2;
        a1v += r[1] * w0 + r[2] * w1 + r[3] * w2;
        a2 += r[2] * w0 + r[3] * w1 + r[4] * w2;
        a3 += r[3] * w0 + r[4] * w1 + r[5] * w2;
      }
    }
  }
  float ps = a0 + a1v + a2 + a3;
  float pq = a0 * a0 + a1v * a1v + a2 * a2 + a3 * a3;
  __shared__ float sh[512];
  sh[threadIdx.x] = ps;
  sh[256 + threadIdx.x] = pq;
  __syncthreads();
  for (int s = 128; s > 0; s >>= 1) {
    if (threadIdx.x < (unsigned)s) {
      sh[threadIdx.x] += sh[threadIdx.x + s];
      sh[256 + threadIdx.x] += sh[256 + threadIdx.x + s];
    }
    __syncthreads();
  }
  if (threadIdx.x == 0) {
    atomicAdd(&sum[co], sh[0]);
    atomicAdd(&sq[co], sh[256]);
  }
}

__global__ void bn3_final_kernel(float* __restrict__ S, const float* __restrict__ g2f,
                                 const float* __restrict__ b2f, const float* __restrict__ gdf,
                                 const float* __restrict__ bdf) {
  int t = threadIdx.x;  // 64 threads
  if (t < 32) {
    float mean = S[2048 + t] / (float)DHW;
    float var = S[2080 + t] / (float)DHW - mean * mean;
    float sc = g2f[t] * rsqrtf(var + EPS);
    S[2176 + t] = sc;
    S[2208 + t] = b2f[t] - mean * sc;
  } else {
    int c = t - 32;
    float mean = S[2112 + c] / (float)DHW;
    float var = S[2144 + c] / (float)DHW - mean * mean;
    float sc = gdf[c] * rsqrtf(var + EPS);
    S[2240 + c] = sc;
    S[2272 + c] = bdf[c] - mean * sc;
  }
}

__global__ __launch_bounds__(256) void final_conv_kernel(const u16* __restrict__ a1,
                                                         const void* __restrict__ x,
                                                         const float* __restrict__ w2f,
                                                         const float* __restrict__ wdf,
                                                         const float* __restrict__ S,
                                                         const int* __restrict__ flagp,
                                                         void* __restrict__ out) {
  const int bf = flagp[0];
  const int bid = blockIdx.x;
  const int co = bid & 31;
  const int rem = bid >> 5;
  const int d = rem / 20;
  const int p = (rem % 20) * 256 + threadIdx.x;
  const int y = p / 40;
  const int x0 = (p % 40) * 4;

  float a0 = 0.f, a1v = 0.f, a2 = 0.f, a3 = 0.f;
  for (int ci = 0; ci < COUT; ci++) {
#pragma unroll
    for (int kd = 0; kd < 3; kd++) {
      int dd = d - 1 + kd;
      if ((unsigned)dd >= (unsigned)D) continue;
      const int base = ci * DHW + dd * HW;
#pragma unroll
      for (int ky = 0; ky < 3; ky++) {
        int yy = y - 1 + ky;
        if ((unsigned)yy >= (unsigned)H) continue;
        const u16* row = a1 + base + yy * W;
        float r[6];
        {
          ushort4 v4 = *(const ushort4*)(row + x0);
          r[1] = bf2f(v4.x); r[2] = bf2f(v4.y); r[3] = bf2f(v4.z); r[4] = bf2f(v4.w);
        }
        r[0] = (x0 > 0) ? bf2f(row[x0 - 1]) : 0.f;
        r[5] = (x0 + 4 < W) ? bf2f(row[x0 + 4]) : 0.f;
        const float* wp = w2f + (((co * COUT + ci) * 3 + kd) * 3 + ky) * 3;
        float w0 = wp[0], w1 = wp[1], w2 = wp[2];
        a0 += r[0] * w0 + r[1] * w1 + r[2] * w2;
        a1v += r[1] * w0 + r[2] * w1 + r[3] * w2;
        a2 += r[2] * w0 + r[3] * w1 + r[4] * w2;
        a3 += r[3] * w0 + r[4] * w1 + r[5] * w2;
      }
    }
  }
  float b0 = 0.f, b1v = 0.f, b2v = 0.f, b3 = 0.f;
  for (int ci = 0; ci < CIN; ci++) {
#pragma unroll
    for (int kd = 0; kd < 3; kd++) {
      int dd = d - 1 + kd;
      if ((unsigned)dd >= (unsigned)D) continue;
      const int base = ci * DHW + dd * HW;
#pragma unroll
      for (int ky = 0; ky < 3; ky++) {
        int yy = y - 1 + ky;
        if ((unsigned)yy >= (unsigned)H) continue;
        const int rbase = base + yy * W;
        float r[6];
        if (bf) {
          ushort4 v4 = *(const ushort4*)((const u16*)x + rbase + x0);
          r[1] = bf2f(v4.x); r[2] = bf2f(v4.y); r[3] = bf2f(v4.z); r[4] = bf2f(v4.w);
        } else {
          float4 v4 = *(const float4*)((const float*)x + rbase + x0);
          r[1] = v4.x; r[2] = v4.y; r[3] = v4.z; r[4] = v4.w;
        }
        r[0] = (x0 > 0) ? ldin(x, rbase + x0 - 1, bf) : 0.f;
        r[5] = (x0 + 4 < W) ? ldin(x, rbase + x0 + 4, bf) : 0.f;
        const float* wp = wdf + (((co * CIN + ci) * 3 + kd) * 3 + ky) * 3;
        float w0 = wp[0], w1 = wp[1], w2 = wp[2];
        b0 += r[0] * w0 + r[1] * w1 + r[2] * w2;
        b1v += r[1] * w0 + r[2] * w1 + r[3] * w2;
        b2v += r[2] * w0 + r[3] * w1 + r[4] * w2;
        b3 += r[3] * w0 + r[4] * w1 + r[5] * w2;
      }
    }
  }

  float s2 = S[2176 + co], o2 = S[2208 + co];
  float sd = S[2240 + co], od = S[2272 + co];
  float r0 = fmaxf(a0 * s2 + o2 + b0 * sd + od, 0.f);
  float r1 = fmaxf(a1v * s2 + o2 + b1v * sd + od, 0.f);
  float r2 = fmaxf(a2 * s2 + o2 + b2v * sd + od, 0.f);
  float r3 = fmaxf(a3 * s2 + o2 + b3 * sd + od, 0.f);
  int oi = co * DHW + d * HW + y * W + x0;
  if (bf) {
    ushort4 st;
    st.x = f2bf(r0);
    st.y = f2bf(r1);
    st.z = f2bf(r2);
    st.w = f2bf(r3);
    *(ushort4*)((u16*)out + oi) = st;
  } else {
    float4 st;
    st.x = r0;
    st.y = r1;
    st.z = r2;
    st.w = r3;
    *(float4*)((float*)out + oi) = st;
  }
}

extern "C" void kernel_launch(void* const* d_in, const int* in_sizes, int n_in,
                              void* d_out, int out_size, void* d_ws, size_t ws_size,
                              hipStream_t stream) {
  const void* x = d_in[0];
  const void* f = d_in[1];

  char* ws = (char*)d_ws;
  float* S = (float*)ws;
  int* flag = (int*)ws + FLAG_SLOT;
  float* WF = (float*)(ws + WF_OFF);
  u16* a1 = (u16*)(ws + A1_OFF);

  zero_kernel<<<16, 256, 0, stream>>>(S);
  sniff_kernel<<<1, 256, 0, stream>>>((const u16*)x, flag);

  // inputs: x,f,w_off,w_reg,g1,b1,w2,g2,b2,wd,gd,bd
  const int cvt_n[10] = {2592, 4608, 27648, 13824, 32, 32, 32, 32, 32, 32};
  const int cvt_off[10] = {WOFF_O, WREG_O, W2_O, WD_O, G1_O, B1_O, G2_O, B2_O, GD_O, BD_O};
  const int src_idx[10] = {2, 3, 6, 9, 4, 5, 7, 8, 10, 11};
  for (int k = 0; k < 10; k++) {
    cvt_kernel<<<(cvt_n[k] + 255) / 256, 256, 0, stream>>>(d_in[src_idx[k]], WF + cvt_off[k],
                                                           cvt_n[k], flag);
  }

  deform_kernel<<<D * (HW / 256), 256, 0, stream>>>(x, f, WF + WOFF_O, WF + WREG_O, a1, flag);

  bn1_stats_kernel<<<COUT * D, 256, 0, stream>>>(a1, WF + G1_O, WF + B1_O, S);
  bn1_apply_kernel<<<NOUT / 1024, 256, 0, stream>>>(a1, S);

  const size_t need32 = OUT2_OFF + 2ull * NOUT * sizeof(float);  // ~208 MiB: fp32 pairs
  const size_t need16 = OUT2_OFF + 2ull * NOUT * sizeof(u16);    // 128 MiB: bf16 pairs

  if (ws_size >= need16) {
    const int st32 = (ws_size >= need32) ? 1 : 0;
    const size_t esz = st32 ? sizeof(float) : sizeof(u16);
    void* out2 = ws + OUT2_OFF;
    void* outd = ws + OUT2_OFF + (size_t)NOUT * esz;

    conv_store_kernel<<<COUT * D * 20, 256, 0, stream>>>(a1, x, WF + W2_O, WF + WD_O, flag, st32,
                                                         out2, outd, S);
    bn3_final_kernel<<<1, 64, 0, stream>>>(S, WF + G2_O, WF + B2_O, WF + GD_O, WF + BD_O);
    combine_kernel<<<NOUT / 1024, 256, 0, stream>>>(out2, outd, S, flag, st32, d_out);
  } else {
    // proven fallback: stats passes + recompute
    conv_stats_kernel<<<COUT * D * 20, 256, 0, stream>>>(a1, WF + W2_O, COUT, 1, flag, S + 2048,
                                                         S + 2080);
    conv_stats_kernel<<<COUT * D * 20, 256, 0, stream>>>(x, WF + WD_O, CIN, 0, flag, S + 2112,
                                                         S + 2144);
    bn3_final_kernel<<<1, 64, 0, stream>>>(S, WF + G2_O, WF + B2_O, WF + GD_O, WF + BD_O);
    final_conv_kernel<<<COUT * D * 20, 256, 0, stream>>>(a1, x, WF + W2_O, WF + WD_O, S, flag,
                                                         d_out);
  }
}

// Round 2
// 1533.746 us; speedup vs baseline: 5.0628x; 2.7018x over previous
//
#include <hip/hip_runtime.h>

using u16 = unsigned short;

constexpr int CIN = 16, COUT = 32, COFF = 16;
constexpr int D = 32, H = 128, W = 160;
constexpr int HW = H * W;         // 20480
constexpr int DHW = D * HW;       // 655360
constexpr int NOUT = COUT * DHW;  // 20971520
constexpr float EPS = 1e-5f;

// ---- workspace layout (byte offsets) ----
constexpr size_t WF_OFF = 16384;
constexpr size_t A1_OFF = 262144;
constexpr size_t OUT2_OFF = 50331648;  // 48 MiB: conv outputs (a,b) live here when ws permits
constexpr int WOFF_O = 0, WREG_O = 2592, W2_O = 7200, WD_O = 34848;
constexpr int G1_O = 48672, B1_O = 48704, G2_O = 48736, B2_O = 48768, GD_O = 48800, BD_O = 48832;
constexpr int FLAG_SLOT = 3000;

static __device__ __forceinline__ float bf2f(u16 h) {
  unsigned u = ((unsigned)h) << 16;
  float f;
  __builtin_memcpy(&f, &u, 4);
  return f;
}
static __device__ __forceinline__ u16 f2bf(float f) {
  unsigned u;
  __builtin_memcpy(&u, &f, 4);
  u += 0x7fffu + ((u >> 16) & 1u);
  return (u16)(u >> 16);
}
static __device__ __forceinline__ float ldin(const void* p, int i, int bf) {
  float r;
  if (bf) r = bf2f(((const u16*)p)[i]);
  else r = ((const float*)p)[i];
  return r;
}

__global__ __launch_bounds__(256) void zero_kernel(float* __restrict__ S) {
  S[blockIdx.x * 256 + threadIdx.x] = 0.f;
}

__global__ __launch_bounds__(256) void sniff_kernel(const u16* __restrict__ x,
                                                    int* __restrict__ flag) {
  __shared__ int sh[256];
  int cnt = 0;
  for (int i = threadIdx.x; i < 4096; i += 256) {
    int e = (x[i] >> 7) & 0xff;
    cnt += (e >= 96 && e <= 144) ? 1 : 0;
  }
  sh[threadIdx.x] = cnt;
  __syncthreads();
  for (int s = 128; s > 0; s >>= 1) {
    if (threadIdx.x < (unsigned)s) sh[threadIdx.x] += sh[threadIdx.x + s];
    __syncthreads();
  }
  if (threadIdx.x == 0) flag[0] = (sh[0] > 3072) ? 1 : 0;
}

__global__ __launch_bounds__(256) void cvt_kernel(const void* __restrict__ in,
                                                  float* __restrict__ out, int n,
                                                  const int* __restrict__ flagp) {
  int bf = flagp[0];
  int i = blockIdx.x * 256 + threadIdx.x;
  if (i < n) out[i] = ldin(in, i, bf);
}

// Deformable conv: one thread per (d, y, x).  (verbatim from the passing build)
__global__ __launch_bounds__(256) void deform_kernel(const void* __restrict__ x,
                                                     const void* __restrict__ f,
                                                     const float* __restrict__ w_off_f,
                                                     const float* __restrict__ w_reg_f,
                                                     u16* __restrict__ a1,
                                                     const int* __restrict__ flagp) {
  const int bf = flagp[0];
  const int bid = blockIdx.x;
  const int d = bid / (HW / 256);
  const int p = (bid % (HW / 256)) * 256 + threadIdx.x;
  const int y = p / W;
  const int xx = p % W;

  float doff[18];
#pragma unroll
  for (int t = 0; t < 18; t++) doff[t] = 0.f;
  for (int ci = 0; ci < COFF; ci++) {
    const int fbase = ci * DHW + d * HW;
#pragma unroll
    for (int ki = 0; ki < 3; ki++) {
      int yy = y - 1 + ki;
      bool yok = (unsigned)yy < (unsigned)H;
#pragma unroll
      for (int kj = 0; kj < 3; kj++) {
        int xj = xx - 1 + kj;
        float v = (yok && (unsigned)xj < (unsigned)W) ? ldin(f, fbase + yy * W + xj, bf) : 0.f;
        int widx = ci * 9 + ki * 3 + kj;
#pragma unroll
        for (int t = 0; t < 18; t++) doff[t] += v * w_off_f[t * 144 + widx];
      }
    }
  }

  float acc[COUT];
#pragma unroll
  for (int co = 0; co < COUT; co++) acc[co] = 0.f;

#pragma unroll
  for (int t = 0; t < 9; t++) {
    float dy = fminf(fmaxf(doff[2 * t], -1.f), 1.f);
    float dx = fminf(fmaxf(doff[2 * t + 1], -1.f), 1.f);
    float py = (float)(y - 1 + t / 3) + dy;
    float px = (float)(xx - 1 + t % 3) + dx;
    float y0f = floorf(py), x0f = floorf(px);
    float wy1 = py - y0f, wx1 = px - x0f;
    int y0 = (int)y0f, x0i = (int)x0f;
    int y1 = y0 + 1, x1 = x0i + 1;
    bool y0v = (unsigned)y0 < (unsigned)H, y1v = (unsigned)y1 < (unsigned)H;
    bool x0v = (unsigned)x0i < (unsigned)W, x1v = (unsigned)x1 < (unsigned)W;
    float c00 = (y0v && x0v) ? (1.f - wy1) * (1.f - wx1) : 0.f;
    float c01 = (y0v && x1v) ? (1.f - wy1) * wx1 : 0.f;
    float c10 = (y1v && x0v) ? wy1 * (1.f - wx1) : 0.f;
    float c11 = (y1v && x1v) ? wy1 * wx1 : 0.f;
    int y0c = min(max(y0, 0), H - 1) * W, y1c = min(max(y1, 0), H - 1) * W;
    int x0c = min(max(x0i, 0), W - 1), x1c = min(max(x1, 0), W - 1);

    for (int ci = 0; ci < CIN; ci++) {
      const int xbase = ci * DHW + d * HW;
      float s = c00 * ldin(x, xbase + y0c + x0c, bf) + c01 * ldin(x, xbase + y0c + x1c, bf) +
                c10 * ldin(x, xbase + y1c + x0c, bf) + c11 * ldin(x, xbase + y1c + x1c, bf);
#pragma unroll
      for (int co = 0; co < COUT; co++) acc[co] += s * w_reg_f[co * 144 + ci * 9 + t];
    }
  }

#pragma unroll
  for (int co = 0; co < COUT; co++) a1[co * DHW + d * HW + p] = f2bf(acc[co]);
}

__global__ __launch_bounds__(256) void bn1_stats_kernel(const u16* __restrict__ a1,
                                                        const float* __restrict__ g1f,
                                                        const float* __restrict__ b1f,
                                                        float* __restrict__ S) {
  int cd = blockIdx.x;
  int c = cd / D;
  const u16* p = a1 + (size_t)cd * HW;
  float sum = 0.f, sq = 0.f;
  for (int i = threadIdx.x; i < HW; i += 256) {
    float v = bf2f(p[i]);
    sum += v;
    sq += v * v;
  }
  __shared__ float sh[512];
  sh[threadIdx.x] = sum;
  sh[256 + threadIdx.x] = sq;
  __syncthreads();
  for (int s = 128; s > 0; s >>= 1) {
    if (threadIdx.x < (unsigned)s) {
      sh[threadIdx.x] += sh[threadIdx.x + s];
      sh[256 + threadIdx.x] += sh[256 + threadIdx.x + s];
    }
    __syncthreads();
  }
  if (threadIdx.x == 0) {
    float mean = sh[0] / (float)HW;
    float var = sh[256] / (float)HW - mean * mean;
    float sc = g1f[c] * rsqrtf(var + EPS);
    S[cd] = sc;
    S[1024 + cd] = b1f[c] - mean * sc;
  }
}

__global__ __launch_bounds__(256) void bn1_apply_kernel(u16* __restrict__ a1,
                                                        const float* __restrict__ S) {
  int i = (blockIdx.x * 256 + threadIdx.x) * 4;
  int cd = i / HW;
  float sc = S[cd], of = S[1024 + cd];
  ushort4 v = *(const ushort4*)(a1 + i);
  ushort4 r;
  r.x = f2bf(fmaxf(bf2f(v.x) * sc + of, 0.f));
  r.y = f2bf(fmaxf(bf2f(v.y) * sc + of, 0.f));
  r.z = f2bf(fmaxf(bf2f(v.z) * sc + of, 0.f));
  r.w = f2bf(fmaxf(bf2f(v.w) * sc + of, 0.f));
  *(ushort4*)(a1 + i) = r;
}

// -------- main conv (from a1, 32 ci): 8 output channels per thread --------
// Each thread: 4 consecutive pixels x 8 co.  Input rows loaded once feed 96 FMAs.
__global__ __launch_bounds__(256) void conv_main_store_kernel(const u16* __restrict__ a1,
                                                              const float* __restrict__ w2f,
                                                              int st32, void* __restrict__ out2,
                                                              float* __restrict__ S) {
  const int bid = blockIdx.x;
  const int cg = bid & 3;  // co group innermost: 4 blocks share the input tile
  const int rem = bid >> 2;
  const int d = rem / 20;
  const int p = (rem % 20) * 256 + threadIdx.x;
  const int y = p / 40;
  const int x0 = (p % 40) * 4;
  const int co0 = cg * 8;

  float acc[8][4];
#pragma unroll
  for (int t = 0; t < 8; t++)
#pragma unroll
    for (int k = 0; k < 4; k++) acc[t][k] = 0.f;

  for (int ci = 0; ci < COUT; ci++) {
#pragma unroll
    for (int kd = 0; kd < 3; kd++) {
      int dd = d - 1 + kd;
      if ((unsigned)dd >= (unsigned)D) continue;
      const int base = ci * DHW + dd * HW;
#pragma unroll
      for (int ky = 0; ky < 3; ky++) {
        int yy = y - 1 + ky;
        if ((unsigned)yy >= (unsigned)H) continue;
        const u16* row = a1 + base + yy * W;
        float r0, r1, r2, r3, r4, r5;
        {
          ushort4 v4 = *(const ushort4*)(row + x0);
          r1 = bf2f(v4.x); r2 = bf2f(v4.y); r3 = bf2f(v4.z); r4 = bf2f(v4.w);
        }
        r0 = (x0 > 0) ? bf2f(row[x0 - 1]) : 0.f;
        r5 = (x0 + 4 < W) ? bf2f(row[x0 + 4]) : 0.f;
        const float* wb = w2f + (co0 * COUT + ci) * 27 + kd * 9 + ky * 3;
#pragma unroll
        for (int t = 0; t < 8; t++) {
          const float* wp = wb + t * (COUT * 27);
          float w0 = wp[0], w1 = wp[1], w2 = wp[2];
          acc[t][0] += r0 * w0 + r1 * w1 + r2 * w2;
          acc[t][1] += r1 * w0 + r2 * w1 + r3 * w2;
          acc[t][2] += r2 * w0 + r3 * w1 + r4 * w2;
          acc[t][3] += r3 * w0 + r4 * w1 + r5 * w2;
        }
      }
    }
  }

  // store
#pragma unroll
  for (int t = 0; t < 8; t++) {
    const int oi = (co0 + t) * DHW + d * HW + y * W + x0;
    if (st32) {
      float4 v;
      v.x = acc[t][0]; v.y = acc[t][1]; v.z = acc[t][2]; v.w = acc[t][3];
      *(float4*)((float*)out2 + oi) = v;
    } else {
      ushort4 v;
      v.x = f2bf(acc[t][0]); v.y = f2bf(acc[t][1]); v.z = f2bf(acc[t][2]); v.w = f2bf(acc[t][3]);
      *(ushort4*)((u16*)out2 + oi) = v;
    }
  }

  // per-co stats (sum, sumsq)
  __shared__ float sh[512];
#pragma unroll
  for (int t = 0; t < 8; t++) {
    float ps = acc[t][0] + acc[t][1] + acc[t][2] + acc[t][3];
    float pq = acc[t][0] * acc[t][0] + acc[t][1] * acc[t][1] + acc[t][2] * acc[t][2] +
               acc[t][3] * acc[t][3];
    sh[threadIdx.x] = ps;
    sh[256 + threadIdx.x] = pq;
    __syncthreads();
    for (int s = 128; s > 0; s >>= 1) {
      if (threadIdx.x < (unsigned)s) {
        sh[threadIdx.x] += sh[threadIdx.x + s];
        sh[256 + threadIdx.x] += sh[256 + threadIdx.x + s];
      }
      __syncthreads();
    }
    if (threadIdx.x == 0) {
      atomicAdd(&S[2048 + co0 + t], sh[0]);
      atomicAdd(&S[2080 + co0 + t], sh[256]);
    }
    __syncthreads();
  }
}

// -------- identity conv (from x, 16 ci): 8 output channels per thread --------
__global__ __launch_bounds__(256) void conv_id_store_kernel(const void* __restrict__ x,
                                                            const float* __restrict__ wdf,
                                                            const int* __restrict__ flagp,
                                                            int st32, void* __restrict__ outd,
                                                            float* __restrict__ S) {
  const int bf = flagp[0];
  const int bid = blockIdx.x;
  const int cg = bid & 3;
  const int rem = bid >> 2;
  const int d = rem / 20;
  const int p = (rem % 20) * 256 + threadIdx.x;
  const int y = p / 40;
  const int x0 = (p % 40) * 4;
  const int co0 = cg * 8;

  float acc[8][4];
#pragma unroll
  for (int t = 0; t < 8; t++)
#pragma unroll
    for (int k = 0; k < 4; k++) acc[t][k] = 0.f;

  for (int ci = 0; ci < CIN; ci++) {
#pragma unroll
    for (int kd = 0; kd < 3; kd++) {
      int dd = d - 1 + kd;
      if ((unsigned)dd >= (unsigned)D) continue;
      const int base = ci * DHW + dd * HW;
#pragma unroll
      for (int ky = 0; ky < 3; ky++) {
        int yy = y - 1 + ky;
        if ((unsigned)yy >= (unsigned)H) continue;
        const int rbase = base + yy * W;
        float r0, r1, r2, r3, r4, r5;
        if (bf) {
          ushort4 v4 = *(const ushort4*)((const u16*)x + rbase + x0);
          r1 = bf2f(v4.x); r2 = bf2f(v4.y); r3 = bf2f(v4.z); r4 = bf2f(v4.w);
        } else {
          float4 v4 = *(const float4*)((const float*)x + rbase + x0);
          r1 = v4.x; r2 = v4.y; r3 = v4.z; r4 = v4.w;
        }
        r0 = (x0 > 0) ? ldin(x, rbase + x0 - 1, bf) : 0.f;
        r5 = (x0 + 4 < W) ? ldin(x, rbase + x0 + 4, bf) : 0.f;
        const float* wb = wdf + (co0 * CIN + ci) * 27 + kd * 9 + ky * 3;
#pragma unroll
        for (int t = 0; t < 8; t++) {
          const float* wp = wb + t * (CIN * 27);
          float w0 = wp[0], w1 = wp[1], w2 = wp[2];
          acc[t][0] += r0 * w0 + r1 * w1 + r2 * w2;
          acc[t][1] += r1 * w0 + r2 * w1 + r3 * w2;
          acc[t][2] += r2 * w0 + r3 * w1 + r4 * w2;
          acc[t][3] += r3 * w0 + r4 * w1 + r5 * w2;
        }
      }
    }
  }

#pragma unroll
  for (int t = 0; t < 8; t++) {
    const int oi = (co0 + t) * DHW + d * HW + y * W + x0;
    if (st32) {
      float4 v;
      v.x = acc[t][0]; v.y = acc[t][1]; v.z = acc[t][2]; v.w = acc[t][3];
      *(float4*)((float*)outd + oi) = v;
    } else {
      ushort4 v;
      v.x = f2bf(acc[t][0]); v.y = f2bf(acc[t][1]); v.z = f2bf(acc[t][2]); v.w = f2bf(acc[t][3]);
      *(ushort4*)((u16*)outd + oi) = v;
    }
  }

  __shared__ float sh[512];
#pragma unroll
  for (int t = 0; t < 8; t++) {
    float ps = acc[t][0] + acc[t][1] + acc[t][2] + acc[t][3];
    float pq = acc[t][0] * acc[t][0] + acc[t][1] * acc[t][1] + acc[t][2] * acc[t][2] +
               acc[t][3] * acc[t][3];
    sh[threadIdx.x] = ps;
    sh[256 + threadIdx.x] = pq;
    __syncthreads();
    for (int s = 128; s > 0; s >>= 1) {
      if (threadIdx.x < (unsigned)s) {
        sh[threadIdx.x] += sh[threadIdx.x + s];
        sh[256 + threadIdx.x] += sh[256 + threadIdx.x + s];
      }
      __syncthreads();
    }
    if (threadIdx.x == 0) {
      atomicAdd(&S[2112 + co0 + t], sh[0]);
      atomicAdd(&S[2144 + co0 + t], sh[256]);
    }
    __syncthreads();
  }
}

// elementwise: out = relu(a*s2+o2 + b*sd+od)
__global__ __launch_bounds__(256) void combine_kernel(const void* __restrict__ out2,
                                                      const void* __restrict__ outd,
                                                      const float* __restrict__ S,
                                                      const int* __restrict__ flagp, int st32,
                                                      void* __restrict__ out) {
  int i = (blockIdx.x * 256 + threadIdx.x) * 4;
  int co = i / DHW;
  float s2 = S[2176 + co], o2 = S[2208 + co];
  float sd = S[2240 + co], od = S[2272 + co];
  float a[4], b[4];
  if (st32) {
    float4 va = *(const float4*)((const float*)out2 + i);
    a[0] = va.x; a[1] = va.y; a[2] = va.z; a[3] = va.w;
    float4 vb = *(const float4*)((const float*)outd + i);
    b[0] = vb.x; b[1] = vb.y; b[2] = vb.z; b[3] = vb.w;
  } else {
    ushort4 va = *(const ushort4*)((const u16*)out2 + i);
    a[0] = bf2f(va.x); a[1] = bf2f(va.y); a[2] = bf2f(va.z); a[3] = bf2f(va.w);
    ushort4 vb = *(const ushort4*)((const u16*)outd + i);
    b[0] = bf2f(vb.x); b[1] = bf2f(vb.y); b[2] = bf2f(vb.z); b[3] = bf2f(vb.w);
  }
  float r[4];
#pragma unroll
  for (int k = 0; k < 4; k++) r[k] = fmaxf(a[k] * s2 + o2 + b[k] * sd + od, 0.f);
  int bf = flagp[0];
  if (bf) {
    ushort4 st;
    st.x = f2bf(r[0]); st.y = f2bf(r[1]); st.z = f2bf(r[2]); st.w = f2bf(r[3]);
    *(ushort4*)((u16*)out + i) = st;
  } else {
    float4 st;
    st.x = r[0]; st.y = r[1]; st.z = r[2]; st.w = r[3];
    *(float4*)((float*)out + i) = st;
  }
}

// -------- fallback path (verbatim from the proven build) --------
__global__ __launch_bounds__(256) void conv_stats_kernel(const void* __restrict__ in,
                                                         const float* __restrict__ wt, int nci,
                                                         int force_bf, const int* __restrict__ flagp,
                                                         float* __restrict__ sum,
                                                         float* __restrict__ sq) {
  const int bf = force_bf ? 1 : flagp[0];
  const int bid = blockIdx.x;
  const int co = bid & 31;
  const int rem = bid >> 5;
  const int d = rem / 20;
  const int p = (rem % 20) * 256 + threadIdx.x;
  const int y = p / 40;
  const int x0 = (p % 40) * 4;

  float a0 = 0.f, a1v = 0.f, a2 = 0.f, a3 = 0.f;
  for (int ci = 0; ci < nci; ci++) {
#pragma unroll
    for (int kd = 0; kd < 3; kd++) {
      int dd = d - 1 + kd;
      if ((unsigned)dd >= (unsigned)D) continue;
      const int base = ci * DHW + dd * HW;
#pragma unroll
      for (int ky = 0; ky < 3; ky++) {
        int yy = y - 1 + ky;
        if ((unsigned)yy >= (unsigned)H) continue;
        const int rbase = base + yy * W;
        float r[6];
        if (bf) {
          ushort4 v4 = *(const ushort4*)((const u16*)in + rbase + x0);
          r[1] = bf2f(v4.x); r[2] = bf2f(v4.y); r[3] = bf2f(v4.z); r[4] = bf2f(v4.w);
        } else {
          float4 v4 = *(const float4*)((const float*)in + rbase + x0);
          r[1] = v4.x; r[2] = v4.y; r[3] = v4.z; r[4] = v4.w;
        }
        r[0] = (x0 > 0) ? ldin(in, rbase + x0 - 1, bf) : 0.f;
        r[5] = (x0 + 4 < W) ? ldin(in, rbase + x0 + 4, bf) : 0.f;
        const float* wp = wt + (((co * nci + ci) * 3 + kd) * 3 + ky) * 3;
        float w0 = wp[0], w1 = wp[1], w2 = wp[2];
        a0 += r[0] * w0 + r[1] * w1 + r[2] * w2;
        a1v += r[1] * w0 + r[2] * w1 + r[3] * w2;
        a2 += r[2] * w0 + r[3] * w1 + r[4] * w2;
        a3 += r[3] * w0 + r[4] * w1 + r[5] * w2;
      }
    }
  }
  float ps = a0 + a1v + a2 + a3;
  float pq = a0 * a0 + a1v * a1v + a2 * a2 + a3 * a3;
  __shared__ float sh[512];
  sh[threadIdx.x] = ps;
  sh[256 + threadIdx.x] = pq;
  __syncthreads();
  for (int s = 128; s > 0; s >>= 1) {
    if (threadIdx.x < (unsigned)s) {
      sh[threadIdx.x] += sh[threadIdx.x + s];
      sh[256 + threadIdx.x] += sh[256 + threadIdx.x + s];
    }
    __syncthreads();
  }
  if (threadIdx.x == 0) {
    atomicAdd(&sum[co], sh[0]);
    atomicAdd(&sq[co], sh[256]);
  }
}

__global__ void bn3_final_kernel(float* __restrict__ S, const float* __restrict__ g2f,
                                 const float* __restrict__ b2f, const float* __restrict__ gdf,
                                 const float* __restrict__ bdf) {
  int t = threadIdx.x;  // 64 threads
  if (t < 32) {
    float mean = S[2048 + t] / (float)DHW;
    float var = S[2080 + t] / (float)DHW - mean * mean;
    float sc = g2f[t] * rsqrtf(var + EPS);
    S[2176 + t] = sc;
    S[2208 + t] = b2f[t] - mean * sc;
  } else {
    int c = t - 32;
    float mean = S[2112 + c] / (float)DHW;
    float var = S[2144 + c] / (float)DHW - mean * mean;
    float sc = gdf[c] * rsqrtf(var + EPS);
    S[2240 + c] = sc;
    S[2272 + c] = bdf[c] - mean * sc;
  }
}

__global__ __launch_bounds__(256) void final_conv_kernel(const u16* __restrict__ a1,
                                                         const void* __restrict__ x,
                                                         const float* __restrict__ w2f,
                                                         const float* __restrict__ wdf,
                                                         const float* __restrict__ S,
                                                         const int* __restrict__ flagp,
                                                         void* __restrict__ out) {
  const int bf = flagp[0];
  const int bid = blockIdx.x;
  const int co = bid & 31;
  const int rem = bid >> 5;
  const int d = rem / 20;
  const int p = (rem % 20) * 256 + threadIdx.x;
  const int y = p / 40;
  const int x0 = (p % 40) * 4;

  float a0 = 0.f, a1v = 0.f, a2 = 0.f, a3 = 0.f;
  for (int ci = 0; ci < COUT; ci++) {
#pragma unroll
    for (int kd = 0; kd < 3; kd++) {
      int dd = d - 1 + kd;
      if ((unsigned)dd >= (unsigned)D) continue;
      const int base = ci * DHW + dd * HW;
#pragma unroll
      for (int ky = 0; ky < 3; ky++) {
        int yy = y - 1 + ky;
        if ((unsigned)yy >= (unsigned)H) continue;
        const u16* row = a1 + base + yy * W;
        float r[6];
        {
          ushort4 v4 = *(const ushort4*)(row + x0);
          r[1] = bf2f(v4.x); r[2] = bf2f(v4.y); r[3] = bf2f(v4.z); r[4] = bf2f(v4.w);
        }
        r[0] = (x0 > 0) ? bf2f(row[x0 - 1]) : 0.f;
        r[5] = (x0 + 4 < W) ? bf2f(row[x0 + 4]) : 0.f;
        const float* wp = w2f + (((co * COUT + ci) * 3 + kd) * 3 + ky) * 3;
        float w0 = wp[0], w1 = wp[1], w2 = wp[2];
        a0 += r[0] * w0 + r[1] * w1 + r[2] * w2;
        a1v += r[1] * w0 + r[2] * w1 + r[3] * w2;
        a2 += r[2] * w0 + r[3] * w1 + r[4] * w2;
        a3 += r[3] * w0 + r[4] * w1 + r[5] * w2;
      }
    }
  }
  float b0 = 0.f, b1v = 0.f, b2v = 0.f, b3 = 0.f;
  for (int ci = 0; ci < CIN; ci++) {
#pragma unroll
    for (int kd = 0; kd < 3; kd++) {
      int dd = d - 1 + kd;
      if ((unsigned)dd >= (unsigned)D) continue;
      const int base = ci * DHW + dd * HW;
#pragma unroll
      for (int ky = 0; ky < 3; ky++) {
        int yy = y - 1 + ky;
        if ((unsigned)yy >= (unsigned)H) continue;
        const int rbase = base + yy * W;
        float r[6];
        if (bf) {
          ushort4 v4 = *(const ushort4*)((const u16*)x + rbase + x0);
          r[1] = bf2f(v4.x); r[2] = bf2f(v4.y); r[3] = bf2f(v4.z); r[4] = bf2f(v4.w);
        } else {
          float4 v4 = *(const float4*)((const float*)x + rbase + x0);
          r[1] = v4.x; r[2] = v4.y; r[3] = v4.z; r[4] = v4.w;
        }
        r[0] = (x0 > 0) ? ldin(x, rbase + x0 - 1, bf) : 0.f;
        r[5] = (x0 + 4 < W) ? ldin(x, rbase + x0 + 4, bf) : 0.f;
        const float* wp = wdf + (((co * CIN + ci) * 3 + kd) * 3 + ky) * 3;
        float w0 = wp[0], w1 = wp[1], w2 = wp[2];
        b0 += r[0] * w0 + r[1] * w1 + r[2] * w2;
        b1v += r[1] * w0 + r[2] * w1 + r[3] * w2;
        b2v += r[2] * w0 + r[3] * w1 + r[4] * w2;
        b3 += r[3] * w0 + r[4] * w1 + r[5] * w2;
      }
    }
  }

  float s2 = S[2176 + co], o2 = S[2208 + co];
  float sd = S[2240 + co], od = S[2272 + co];
  float r0 = fmaxf(a0 * s2 + o2 + b0 * sd + od, 0.f);
  float r1 = fmaxf(a1v * s2 + o2 + b1v * sd + od, 0.f);
  float r2 = fmaxf(a2 * s2 + o2 + b2v * sd + od, 0.f);
  float r3 = fmaxf(a3 * s2 + o2 + b3 * sd + od, 0.f);
  int oi = co * DHW + d * HW + y * W + x0;
  if (bf) {
    ushort4 st;
    st.x = f2bf(r0);
    st.y = f2bf(r1);
    st.z = f2bf(r2);
    st.w = f2bf(r3);
    *(ushort4*)((u16*)out + oi) = st;
  } else {
    float4 st;
    st.x = r0;
    st.y = r1;
    st.z = r2;
    st.w = r3;
    *(float4*)((float*)out + oi) = st;
  }
}

extern "C" void kernel_launch(void* const* d_in, const int* in_sizes, int n_in,
                              void* d_out, int out_size, void* d_ws, size_t ws_size,
                              hipStream_t stream) {
  const void* x = d_in[0];
  const void* f = d_in[1];

  char* ws = (char*)d_ws;
  float* S = (float*)ws;
  int* flag = (int*)ws + FLAG_SLOT;
  float* WF = (float*)(ws + WF_OFF);
  u16* a1 = (u16*)(ws + A1_OFF);

  zero_kernel<<<16, 256, 0, stream>>>(S);
  sniff_kernel<<<1, 256, 0, stream>>>((const u16*)x, flag);

  // inputs: x,f,w_off,w_reg,g1,b1,w2,g2,b2,wd,gd,bd
  const int cvt_n[10] = {2592, 4608, 27648, 13824, 32, 32, 32, 32, 32, 32};
  const int cvt_off[10] = {WOFF_O, WREG_O, W2_O, WD_O, G1_O, B1_O, G2_O, B2_O, GD_O, BD_O};
  const int src_idx[10] = {2, 3, 6, 9, 4, 5, 7, 8, 10, 11};
  for (int k = 0; k < 10; k++) {
    cvt_kernel<<<(cvt_n[k] + 255) / 256, 256, 0, stream>>>(d_in[src_idx[k]], WF + cvt_off[k],
                                                           cvt_n[k], flag);
  }

  deform_kernel<<<D * (HW / 256), 256, 0, stream>>>(x, f, WF + WOFF_O, WF + WREG_O, a1, flag);

  bn1_stats_kernel<<<COUT * D, 256, 0, stream>>>(a1, WF + G1_O, WF + B1_O, S);
  bn1_apply_kernel<<<NOUT / 1024, 256, 0, stream>>>(a1, S);

  const size_t need32 = OUT2_OFF + 2ull * NOUT * sizeof(float);  // ~208 MiB: fp32 pairs
  const size_t need16 = OUT2_OFF + 2ull * NOUT * sizeof(u16);    // 128 MiB: bf16 pairs

  if (ws_size >= need16) {
    const int st32 = (ws_size >= need32) ? 1 : 0;
    const size_t esz = st32 ? sizeof(float) : sizeof(u16);
    void* out2 = ws + OUT2_OFF;
    void* outd = ws + OUT2_OFF + (size_t)NOUT * esz;

    conv_main_store_kernel<<<4 * D * 20, 256, 0, stream>>>(a1, WF + W2_O, st32, out2, S);
    conv_id_store_kernel<<<4 * D * 20, 256, 0, stream>>>(x, WF + WD_O, flag, st32, outd, S);
    bn3_final_kernel<<<1, 64, 0, stream>>>(S, WF + G2_O, WF + B2_O, WF + GD_O, WF + BD_O);
    combine_kernel<<<NOUT / 1024, 256, 0, stream>>>(out2, outd, S, flag, st32, d_out);
  } else {
    // proven fallback: stats passes + recompute
    conv_stats_kernel<<<COUT * D * 20, 256, 0, stream>>>(a1, WF + W2_O, COUT, 1, flag, S + 2048,
                                                         S + 2080);
    conv_stats_kernel<<<COUT * D * 20, 256, 0, stream>>>(x, WF + WD_O, CIN, 0, flag, S + 2112,
                                                         S + 2144);
    bn3_final_kernel<<<1, 64, 0, stream>>>(S, WF + G2_O, WF + B2_O, WF + GD_O, WF + BD_O);
    final_conv_kernel<<<COUT * D * 20, 256, 0, stream>>>(a1, x, WF + W2_O, WF + WD_O, S, flag,
                                                         d_out);
  }
}

// Round 3
// 1064.615 us; speedup vs baseline: 7.2937x; 1.4407x over previous
//
#include <hip/hip_runtime.h>

using u16 = unsigned short;

constexpr int CIN = 16, COUT = 32, COFF = 16;
constexpr int D = 32, H = 128, W = 160;
constexpr int HW = H * W;         // 20480
constexpr int DHW = D * HW;       // 655360
constexpr int NOUT = COUT * DHW;  // 20971520
constexpr float EPS = 1e-5f;

// ---- workspace layout (byte offsets) ----
constexpr size_t WF_OFF = 16384;
constexpr size_t A1_OFF = 262144;           // a1ch channels-last bf16: 32ch*DHW*2 = 41943040
constexpr size_t XCH_OFF = 50331648;        // xch channels-last bf16 (16 real + 16 zero): 41943040
constexpr size_t W2F_OFF = 94371840;        // packed w2 fragments: 55296 B
constexpr size_t WDF_OFF = 94437376;        // packed wd fragments: 55296 B
constexpr size_t NEED_MFMA = 100663296;     // 96 MiB
constexpr int WOFF_O = 0, WREG_O = 2592, W2_O = 7200, WD_O = 34848;
constexpr int G1_O = 48672, B1_O = 48704, G2_O = 48736, B2_O = 48768, GD_O = 48800, BD_O = 48832;
constexpr int FLAG_SLOT = 3000;

typedef short bf16x8 __attribute__((ext_vector_type(8)));
typedef float f32x4 __attribute__((ext_vector_type(4)));

static __device__ __forceinline__ float bf2f(u16 h) {
  unsigned u = ((unsigned)h) << 16;
  float f;
  __builtin_memcpy(&f, &u, 4);
  return f;
}
static __device__ __forceinline__ u16 f2bf(float f) {
  unsigned u;
  __builtin_memcpy(&u, &f, 4);
  u += 0x7fffu + ((u >> 16) & 1u);
  return (u16)(u >> 16);
}
static __device__ __forceinline__ float ldin(const void* p, int i, int bf) {
  float r;
  if (bf) r = bf2f(((const u16*)p)[i]);
  else r = ((const float*)p)[i];
  return r;
}

__global__ __launch_bounds__(256) void zero_kernel(float* __restrict__ S) {
  S[blockIdx.x * 256 + threadIdx.x] = 0.f;
}

__global__ __launch_bounds__(256) void sniff_kernel(const u16* __restrict__ x,
                                                    int* __restrict__ flag) {
  __shared__ int sh[256];
  int cnt = 0;
  for (int i = threadIdx.x; i < 4096; i += 256) {
    int e = (x[i] >> 7) & 0xff;
    cnt += (e >= 96 && e <= 144) ? 1 : 0;
  }
  sh[threadIdx.x] = cnt;
  __syncthreads();
  for (int s = 128; s > 0; s >>= 1) {
    if (threadIdx.x < (unsigned)s) sh[threadIdx.x] += sh[threadIdx.x + s];
    __syncthreads();
  }
  if (threadIdx.x == 0) flag[0] = (sh[0] > 3072) ? 1 : 0;
}

__global__ __launch_bounds__(256) void cvt_kernel(const void* __restrict__ in,
                                                  float* __restrict__ out, int n,
                                                  const int* __restrict__ flagp) {
  int bf = flagp[0];
  int i = blockIdx.x * 256 + threadIdx.x;
  if (i < n) out[i] = ldin(in, i, bf);
}

// pack weight fragments: dst[t] with t = ((tap*2+cotile)*64 + lane)*8 + j
// value = W[co = cotile*16 + (lane&15)][k = (lane>>4)*8 + j] (0 if k >= nci), bf16.
__global__ __launch_bounds__(256) void pack_frag_kernel(const float* __restrict__ src,
                                                        u16* __restrict__ dst, int nci) {
  int t = blockIdx.x * 256 + threadIdx.x;
  if (t >= 27648) return;
  int j = t & 7;
  int l = (t >> 3) & 63;
  int cotile = (t >> 9) & 1;
  int tap = t >> 10;
  int co = cotile * 16 + (l & 15);
  int k = (l >> 4) * 8 + j;
  float v = (k < nci) ? src[(co * nci + k) * 27 + tap] : 0.f;
  dst[t] = f2bf(v);
}

// transpose x -> channels-last bf16, padded to 32 channels (upper 16 zero)
__global__ __launch_bounds__(256) void xpose_kernel(const void* __restrict__ x,
                                                    u16* __restrict__ xch,
                                                    const int* __restrict__ flagp) {
  const int bf = flagp[0];
  __shared__ u16 lt[16][258];
  const int base = blockIdx.x * 256;
  const int t = threadIdx.x;
#pragma unroll
  for (int ci = 0; ci < 16; ci++) lt[ci][t] = f2bf(ldin(x, ci * DHW + base + t, bf));
  __syncthreads();
  const size_t pb = (size_t)(base + t) * 32;
  unsigned v[8];
#pragma unroll
  for (int m = 0; m < 8; m++)
    v[m] = (unsigned)lt[2 * m][t] | ((unsigned)lt[2 * m + 1][t] << 16);
  uint4 u0, u1, z;
  u0.x = v[0]; u0.y = v[1]; u0.z = v[2]; u0.w = v[3];
  u1.x = v[4]; u1.y = v[5]; u1.z = v[6]; u1.w = v[7];
  z.x = z.y = z.z = z.w = 0;
  *(uint4*)(xch + pb) = u0;
  *(uint4*)(xch + pb + 8) = u1;
  *(uint4*)(xch + pb + 16) = z;
  *(uint4*)(xch + pb + 24) = z;
}

// Deformable conv -> channels-last bf16 a1ch + fused BN1 stats (per (c,d)).
__global__ __launch_bounds__(256) void deform_ch_kernel(const void* __restrict__ x,
                                                        const void* __restrict__ f,
                                                        const float* __restrict__ w_off_f,
                                                        const float* __restrict__ w_reg_f,
                                                        u16* __restrict__ a1ch,
                                                        const int* __restrict__ flagp,
                                                        float* __restrict__ S) {
  const int bf = flagp[0];
  const int bid = blockIdx.x;
  const int d = bid / (HW / 256);
  const int p = (bid % (HW / 256)) * 256 + threadIdx.x;
  const int y = p / W;
  const int xx = p % W;

  float doff[18];
#pragma unroll
  for (int t = 0; t < 18; t++) doff[t] = 0.f;
  for (int ci = 0; ci < COFF; ci++) {
    const int fbase = ci * DHW + d * HW;
#pragma unroll
    for (int ki = 0; ki < 3; ki++) {
      int yy = y - 1 + ki;
      bool yok = (unsigned)yy < (unsigned)H;
#pragma unroll
      for (int kj = 0; kj < 3; kj++) {
        int xj = xx - 1 + kj;
        float v = (yok && (unsigned)xj < (unsigned)W) ? ldin(f, fbase + yy * W + xj, bf) : 0.f;
        int widx = ci * 9 + ki * 3 + kj;
#pragma unroll
        for (int t = 0; t < 18; t++) doff[t] += v * w_off_f[t * 144 + widx];
      }
    }
  }

  float acc[COUT];
#pragma unroll
  for (int co = 0; co < COUT; co++) acc[co] = 0.f;

#pragma unroll
  for (int t = 0; t < 9; t++) {
    float dy = fminf(fmaxf(doff[2 * t], -1.f), 1.f);
    float dx = fminf(fmaxf(doff[2 * t + 1], -1.f), 1.f);
    float py = (float)(y - 1 + t / 3) + dy;
    float px = (float)(xx - 1 + t % 3) + dx;
    float y0f = floorf(py), x0f = floorf(px);
    float wy1 = py - y0f, wx1 = px - x0f;
    int y0 = (int)y0f, x0i = (int)x0f;
    int y1 = y0 + 1, x1 = x0i + 1;
    bool y0v = (unsigned)y0 < (unsigned)H, y1v = (unsigned)y1 < (unsigned)H;
    bool x0v = (unsigned)x0i < (unsigned)W, x1v = (unsigned)x1 < (unsigned)W;
    float c00 = (y0v && x0v) ? (1.f - wy1) * (1.f - wx1) : 0.f;
    float c01 = (y0v && x1v) ? (1.f - wy1) * wx1 : 0.f;
    float c10 = (y1v && x0v) ? wy1 * (1.f - wx1) : 0.f;
    float c11 = (y1v && x1v) ? wy1 * wx1 : 0.f;
    int y0c = min(max(y0, 0), H - 1) * W, y1c = min(max(y1, 0), H - 1) * W;
    int x0c = min(max(x0i, 0), W - 1), x1c = min(max(x1, 0), W - 1);

    for (int ci = 0; ci < CIN; ci++) {
      const int xbase = ci * DHW + d * HW;
      float s = c00 * ldin(x, xbase + y0c + x0c, bf) + c01 * ldin(x, xbase + y0c + x1c, bf) +
                c10 * ldin(x, xbase + y1c + x0c, bf) + c11 * ldin(x, xbase + y1c + x1c, bf);
#pragma unroll
      for (int co = 0; co < COUT; co++) acc[co] += s * w_reg_f[co * 144 + ci * 9 + t];
    }
  }

  // store channels-last bf16
  u16 hh[COUT];
#pragma unroll
  for (int co = 0; co < COUT; co++) hh[co] = f2bf(acc[co]);
  const size_t pb = ((size_t)d * HW + p) * 32;
#pragma unroll
  for (int k = 0; k < 4; k++) {
    uint4 u;
    u.x = (unsigned)hh[8 * k + 0] | ((unsigned)hh[8 * k + 1] << 16);
    u.y = (unsigned)hh[8 * k + 2] | ((unsigned)hh[8 * k + 3] << 16);
    u.z = (unsigned)hh[8 * k + 4] | ((unsigned)hh[8 * k + 5] << 16);
    u.w = (unsigned)hh[8 * k + 6] | ((unsigned)hh[8 * k + 7] << 16);
    *(uint4*)(a1ch + pb + 8 * k) = u;
  }

  // fused BN1 stats on bf16-rounded values (matches old bn1_stats numerics)
  const int l = threadIdx.x & 63;
  const int wv = threadIdx.x >> 6;
  __shared__ float ls[128], lq[128];
#pragma unroll
  for (int co = 0; co < COUT; co++) {
    float v = bf2f(hh[co]);
    float s = v, qq = v * v;
    s += __shfl_xor(s, 1);  qq += __shfl_xor(qq, 1);
    s += __shfl_xor(s, 2);  qq += __shfl_xor(qq, 2);
    s += __shfl_xor(s, 4);  qq += __shfl_xor(qq, 4);
    s += __shfl_xor(s, 8);  qq += __shfl_xor(qq, 8);
    s += __shfl_xor(s, 16); qq += __shfl_xor(qq, 16);
    s += __shfl_xor(s, 32); qq += __shfl_xor(qq, 32);
    if (l == 0) { ls[wv * 32 + co] = s; lq[wv * 32 + co] = qq; }
  }
  __syncthreads();
  if (threadIdx.x < 32) {
    int c = threadIdx.x;
    float s = ls[c] + ls[32 + c] + ls[64 + c] + ls[96 + c];
    float qq = lq[c] + lq[32 + c] + lq[64 + c] + lq[96 + c];
    atomicAdd(&S[c * D + d], s);
    atomicAdd(&S[1024 + c * D + d], qq);
  }
}

__global__ __launch_bounds__(256) void bn1_scale_kernel(float* __restrict__ S,
                                                        const float* __restrict__ g1f,
                                                        const float* __restrict__ b1f) {
  int cd = blockIdx.x * 256 + threadIdx.x;
  if (cd >= 1024) return;
  int c = cd / D;
  float mean = S[cd] / (float)HW;
  float var = S[1024 + cd] / (float)HW - mean * mean;
  float sc = g1f[c] * rsqrtf(var + EPS);
  S[cd] = sc;
  S[1024 + cd] = b1f[c] - mean * sc;
}

__global__ __launch_bounds__(256) void bn1_apply_ch_kernel(u16* __restrict__ a1ch,
                                                           const float* __restrict__ S) {
  __shared__ float sc[32], of[32];
  const int b = blockIdx.x;
  const int d = b / (HW / 256);
  if (threadIdx.x < 32) {
    sc[threadIdx.x] = S[threadIdx.x * D + d];
    of[threadIdx.x] = S[1024 + threadIdx.x * D + d];
  }
  __syncthreads();
  const size_t pb = ((size_t)b * 256 + threadIdx.x) * 32;
#pragma unroll
  for (int k = 0; k < 4; k++) {
    uint4 u = *(const uint4*)(a1ch + pb + 8 * k);
    unsigned w[4] = {u.x, u.y, u.z, u.w};
    unsigned ov[4];
#pragma unroll
    for (int m = 0; m < 4; m++) {
      int c0 = k * 8 + m * 2;
      float lo = bf2f((u16)(w[m] & 0xffffu));
      float hi = bf2f((u16)(w[m] >> 16));
      lo = fmaxf(lo * sc[c0] + of[c0], 0.f);
      hi = fmaxf(hi * sc[c0 + 1] + of[c0 + 1], 0.f);
      ov[m] = (unsigned)f2bf(lo) | ((unsigned)f2bf(hi) << 16);
    }
    uint4 o;
    o.x = ov[0]; o.y = ov[1]; o.z = ov[2]; o.w = ov[3];
    *(uint4*)(a1ch + pb + 8 * k) = o;
  }
}

// Both 3x3x3 convs for one wave-tile of 16 pixels x 32 co, via MFMA.
// A (weights, M=co x K) and B (patch, K x N=pixels) use the SAME k-labeling,
// so the result is invariant to the hardware's internal k mapping.
static __device__ __forceinline__ void conv_core(const bf16x8* __restrict__ a1v,
                                                 const bf16x8* __restrict__ xv,
                                                 const bf16x8* __restrict__ w2v,
                                                 const bf16x8* __restrict__ wdv,
                                                 int d, int y, int xn, int q, int l,
                                                 f32x4& A0, f32x4& A1, f32x4& B0, f32x4& B1) {
  const bf16x8 zero = {0, 0, 0, 0, 0, 0, 0, 0};
#pragma unroll
  for (int kd = 0; kd < 3; kd++) {
    int dd = d - 1 + kd;
    if ((unsigned)dd >= (unsigned)D) continue;
#pragma unroll
    for (int ky = 0; ky < 3; ky++) {
      int yy = y - 1 + ky;
      if ((unsigned)yy >= (unsigned)H) continue;
      const int rowb = dd * HW + yy * W;
#pragma unroll
      for (int kx = 0; kx < 3; kx++) {
        int xx = xn - 1 + kx;
        bool ok = (unsigned)xx < (unsigned)W;
        int xc = min(max(xx, 0), W - 1);
        int pi = rowb + xc;
        bf16x8 bm = a1v[pi * 4 + q];
        bf16x8 bx = xv[pi * 4 + q];
        if (!ok) { bm = zero; bx = zero; }
        const int tb = (kd * 9 + ky * 3 + kx) * 2;
        bf16x8 am0 = w2v[(tb + 0) * 64 + l];
        bf16x8 am1 = w2v[(tb + 1) * 64 + l];
        bf16x8 ad0 = wdv[(tb + 0) * 64 + l];
        bf16x8 ad1 = wdv[(tb + 1) * 64 + l];
        A0 = __builtin_amdgcn_mfma_f32_16x16x32_bf16(am0, bm, A0, 0, 0, 0);
        A1 = __builtin_amdgcn_mfma_f32_16x16x32_bf16(am1, bm, A1, 0, 0, 0);
        B0 = __builtin_amdgcn_mfma_f32_16x16x32_bf16(ad0, bx, B0, 0, 0, 0);
        B1 = __builtin_amdgcn_mfma_f32_16x16x32_bf16(ad1, bx, B1, 0, 0, 0);
      }
    }
  }
}

// stats pass: per-co sum/sumsq of both conv outputs, nothing stored
__global__ __launch_bounds__(1024) void conv_mfma_stats_kernel(const u16* __restrict__ a1ch,
                                                               const u16* __restrict__ xch,
                                                               const u16* __restrict__ w2f,
                                                               const u16* __restrict__ wdf,
                                                               float* __restrict__ S) {
  const int t = threadIdx.x;
  const int l = t & 63, wv = t >> 6;
  const int n = l & 15, q = l >> 4;
  const int P = blockIdx.x * 256 + wv * 16;
  const int d = P / HW;
  const int rp = P % HW;
  const int y = rp / W, xc0 = rp % W;

  f32x4 A0 = {0.f, 0.f, 0.f, 0.f}, A1 = {0.f, 0.f, 0.f, 0.f};
  f32x4 B0 = {0.f, 0.f, 0.f, 0.f}, B1 = {0.f, 0.f, 0.f, 0.f};
  conv_core((const bf16x8*)a1ch, (const bf16x8*)xch, (const bf16x8*)w2f, (const bf16x8*)wdf,
            d, y, xc0 + n, q, l, A0, A1, B0, B1);

  __shared__ float ls[16 * 64], lq[16 * 64];
#define RED16(ACC, BASE)                                                              \
  {                                                                                   \
    _Pragma("unroll") for (int r = 0; r < 4; r++) {                                   \
      float v = ACC[r];                                                               \
      float s = v, qq = v * v;                                                        \
      s += __shfl_xor(s, 1); qq += __shfl_xor(qq, 1);                                 \
      s += __shfl_xor(s, 2); qq += __shfl_xor(qq, 2);                                 \
      s += __shfl_xor(s, 4); qq += __shfl_xor(qq, 4);                                 \
      s += __shfl_xor(s, 8); qq += __shfl_xor(qq, 8);                                 \
      if (n == 0) {                                                                   \
        int ci = (BASE) + q * 4 + r;                                                  \
        ls[wv * 64 + ci] = s;                                                         \
        lq[wv * 64 + ci] = qq;                                                        \
      }                                                                               \
    }                                                                                 \
  }
  RED16(A0, 0)
  RED16(A1, 16)
  RED16(B0, 32)
  RED16(B1, 48)
#undef RED16
  __syncthreads();
  if (t < 64) {
    float s = 0.f, qq = 0.f;
    for (int w = 0; w < 16; w++) { s += ls[w * 64 + t]; qq += lq[w * 64 + t]; }
    if (t < 32) {
      atomicAdd(&S[2048 + t], s);
      atomicAdd(&S[2080 + t], qq);
    } else {
      atomicAdd(&S[2112 + t - 32], s);
      atomicAdd(&S[2144 + t - 32], qq);
    }
  }
}

__global__ void bn3_final_kernel(float* __restrict__ S, const float* __restrict__ g2f,
                                 const float* __restrict__ b2f, const float* __restrict__ gdf,
                                 const float* __restrict__ bdf) {
  int t = threadIdx.x;  // 64 threads
  if (t < 32) {
    float mean = S[2048 + t] / (float)DHW;
    float var = S[2080 + t] / (float)DHW - mean * mean;
    float sc = g2f[t] * rsqrtf(var + EPS);
    S[2176 + t] = sc;
    S[2208 + t] = b2f[t] - mean * sc;
  } else {
    int c = t - 32;
    float mean = S[2112 + c] / (float)DHW;
    float var = S[2144 + c] / (float)DHW - mean * mean;
    float sc = gdf[c] * rsqrtf(var + EPS);
    S[2240 + c] = sc;
    S[2272 + c] = bdf[c] - mean * sc;
  }
}

// final pass: recompute both convs, fuse BN3 + add + relu, write d_out
__global__ __launch_bounds__(256) void conv_mfma_final_kernel(const u16* __restrict__ a1ch,
                                                              const u16* __restrict__ xch,
                                                              const u16* __restrict__ w2f,
                                                              const u16* __restrict__ wdf,
                                                              const float* __restrict__ S,
                                                              const int* __restrict__ flagp,
                                                              void* __restrict__ out) {
  const int t = threadIdx.x;
  const int l = t & 63, wv = t >> 6;
  const int n = l & 15, q = l >> 4;
  const int P = blockIdx.x * 64 + wv * 16;
  const int d = P / HW;
  const int rp = P % HW;
  const int y = rp / W, xc0 = rp % W;

  f32x4 A0 = {0.f, 0.f, 0.f, 0.f}, A1 = {0.f, 0.f, 0.f, 0.f};
  f32x4 B0 = {0.f, 0.f, 0.f, 0.f}, B1 = {0.f, 0.f, 0.f, 0.f};
  conv_core((const bf16x8*)a1ch, (const bf16x8*)xch, (const bf16x8*)w2f, (const bf16x8*)wdf,
            d, y, xc0 + n, q, l, A0, A1, B0, B1);

  const int bf = flagp[0];
#pragma unroll
  for (int r = 0; r < 4; r++) {
    int co = q * 4 + r;
    {
      float s2 = S[2176 + co], o2 = S[2208 + co];
      float sd = S[2240 + co], od = S[2272 + co];
      float v = fmaxf(A0[r] * s2 + o2 + B0[r] * sd + od, 0.f);
      int ai = co * DHW + P + n;
      if (bf) ((u16*)out)[ai] = f2bf(v);
      else ((float*)out)[ai] = v;
    }
    {
      int c2 = co + 16;
      float s2 = S[2176 + c2], o2 = S[2208 + c2];
      float sd = S[2240 + c2], od = S[2272 + c2];
      float v = fmaxf(A1[r] * s2 + o2 + B1[r] * sd + od, 0.f);
      int ai = c2 * DHW + P + n;
      if (bf) ((u16*)out)[ai] = f2bf(v);
      else ((float*)out)[ai] = v;
    }
  }
}

// ==================== proven fallback path (verbatim) ====================
__global__ __launch_bounds__(256) void deform_kernel(const void* __restrict__ x,
                                                     const void* __restrict__ f,
                                                     const float* __restrict__ w_off_f,
                                                     const float* __restrict__ w_reg_f,
                                                     u16* __restrict__ a1,
                                                     const int* __restrict__ flagp) {
  const int bf = flagp[0];
  const int bid = blockIdx.x;
  const int d = bid / (HW / 256);
  const int p = (bid % (HW / 256)) * 256 + threadIdx.x;
  const int y = p / W;
  const int xx = p % W;

  float doff[18];
#pragma unroll
  for (int t = 0; t < 18; t++) doff[t] = 0.f;
  for (int ci = 0; ci < COFF; ci++) {
    const int fbase = ci * DHW + d * HW;
#pragma unroll
    for (int ki = 0; ki < 3; ki++) {
      int yy = y - 1 + ki;
      bool yok = (unsigned)yy < (unsigned)H;
#pragma unroll
      for (int kj = 0; kj < 3; kj++) {
        int xj = xx - 1 + kj;
        float v = (yok && (unsigned)xj < (unsigned)W) ? ldin(f, fbase + yy * W + xj, bf) : 0.f;
        int widx = ci * 9 + ki * 3 + kj;
#pragma unroll
        for (int t = 0; t < 18; t++) doff[t] += v * w_off_f[t * 144 + widx];
      }
    }
  }

  float acc[COUT];
#pragma unroll
  for (int co = 0; co < COUT; co++) acc[co] = 0.f;

#pragma unroll
  for (int t = 0; t < 9; t++) {
    float dy = fminf(fmaxf(doff[2 * t], -1.f), 1.f);
    float dx = fminf(fmaxf(doff[2 * t + 1], -1.f), 1.f);
    float py = (float)(y - 1 + t / 3) + dy;
    float px = (float)(xx - 1 + t % 3) + dx;
    float y0f = floorf(py), x0f = floorf(px);
    float wy1 = py - y0f, wx1 = px - x0f;
    int y0 = (int)y0f, x0i = (int)x0f;
    int y1 = y0 + 1, x1 = x0i + 1;
    bool y0v = (unsigned)y0 < (unsigned)H, y1v = (unsigned)y1 < (unsigned)H;
    bool x0v = (unsigned)x0i < (unsigned)W, x1v = (unsigned)x1 < (unsigned)W;
    float c00 = (y0v && x0v) ? (1.f - wy1) * (1.f - wx1) : 0.f;
    float c01 = (y0v && x1v) ? (1.f - wy1) * wx1 : 0.f;
    float c10 = (y1v && x0v) ? wy1 * (1.f - wx1) : 0.f;
    float c11 = (y1v && x1v) ? wy1 * wx1 : 0.f;
    int y0c = min(max(y0, 0), H - 1) * W, y1c = min(max(y1, 0), H - 1) * W;
    int x0c = min(max(x0i, 0), W - 1), x1c = min(max(x1, 0), W - 1);

    for (int ci = 0; ci < CIN; ci++) {
      const int xbase = ci * DHW + d * HW;
      float s = c00 * ldin(x, xbase + y0c + x0c, bf) + c01 * ldin(x, xbase + y0c + x1c, bf) +
                c10 * ldin(x, xbase + y1c + x0c, bf) + c11 * ldin(x, xbase + y1c + x1c, bf);
#pragma unroll
      for (int co = 0; co < COUT; co++) acc[co] += s * w_reg_f[co * 144 + ci * 9 + t];
    }
  }

#pragma unroll
  for (int co = 0; co < COUT; co++) a1[co * DHW + d * HW + p] = f2bf(acc[co]);
}

__global__ __launch_bounds__(256) void bn1_stats_kernel(const u16* __restrict__ a1,
                                                        const float* __restrict__ g1f,
                                                        const float* __restrict__ b1f,
                                                        float* __restrict__ S) {
  int cd = blockIdx.x;
  int c = cd / D;
  const u16* p = a1 + (size_t)cd * HW;
  float sum = 0.f, sq = 0.f;
  for (int i = threadIdx.x; i < HW; i += 256) {
    float v = bf2f(p[i]);
    sum += v;
    sq += v * v;
  }
  __shared__ float sh[512];
  sh[threadIdx.x] = sum;
  sh[256 + threadIdx.x] = sq;
  __syncthreads();
  for (int s = 128; s > 0; s >>= 1) {
    if (threadIdx.x < (unsigned)s) {
      sh[threadIdx.x] += sh[threadIdx.x + s];
      sh[256 + threadIdx.x] += sh[256 + threadIdx.x + s];
    }
    __syncthreads();
  }
  if (threadIdx.x == 0) {
    float mean = sh[0] / (float)HW;
    float var = sh[256] / (float)HW - mean * mean;
    float sc = g1f[c] * rsqrtf(var + EPS);
    S[cd] = sc;
    S[1024 + cd] = b1f[c] - mean * sc;
  }
}

__global__ __launch_bounds__(256) void bn1_apply_kernel(u16* __restrict__ a1,
                                                        const float* __restrict__ S) {
  int i = (blockIdx.x * 256 + threadIdx.x) * 4;
  int cd = i / HW;
  float sc = S[cd], of = S[1024 + cd];
  ushort4 v = *(const ushort4*)(a1 + i);
  ushort4 r;
  r.x = f2bf(fmaxf(bf2f(v.x) * sc + of, 0.f));
  r.y = f2bf(fmaxf(bf2f(v.y) * sc + of, 0.f));
  r.z = f2bf(fmaxf(bf2f(v.z) * sc + of, 0.f));
  r.w = f2bf(fmaxf(bf2f(v.w) * sc + of, 0.f));
  *(ushort4*)(a1 + i) = r;
}

__global__ __launch_bounds__(256) void conv_stats_kernel(const void* __restrict__ in,
                                                         const float* __restrict__ wt, int nci,
                                                         int force_bf, const int* __restrict__ flagp,
                                                         float* __restrict__ sum,
                                                         float* __restrict__ sq) {
  const int bf = force_bf ? 1 : flagp[0];
  const int bid = blockIdx.x;
  const int co = bid & 31;
  const int rem = bid >> 5;
  const int d = rem / 20;
  const int p = (rem % 20) * 256 + threadIdx.x;
  const int y = p / 40;
  const int x0 = (p % 40) * 4;

  float a0 = 0.f, a1v = 0.f, a2 = 0.f, a3 = 0.f;
  for (int ci = 0; ci < nci; ci++) {
#pragma unroll
    for (int kd = 0; kd < 3; kd++) {
      int dd = d - 1 + kd;
      if ((unsigned)dd >= (unsigned)D) continue;
      const int base = ci * DHW + dd * HW;
#pragma unroll
      for (int ky = 0; ky < 3; ky++) {
        int yy = y - 1 + ky;
        if ((unsigned)yy >= (unsigned)H) continue;
        const int rbase = base + yy * W;
        float r[6];
        if (bf) {
          ushort4 v4 = *(const ushort4*)((const u16*)in + rbase + x0);
          r[1] = bf2f(v4.x); r[2] = bf2f(v4.y); r[3] = bf2f(v4.z); r[4] = bf2f(v4.w);
        } else {
          float4 v4 = *(const float4*)((const float*)in + rbase + x0);
          r[1] = v4.x; r[2] = v4.y; r[3] = v4.z; r[4] = v4.w;
        }
        r[0] = (x0 > 0) ? ldin(in, rbase + x0 - 1, bf) : 0.f;
        r[5] = (x0 + 4 < W) ? ldin(in, rbase + x0 + 4, bf) : 0.f;
        const float* wp = wt + (((co * nci + ci) * 3 + kd) * 3 + ky) * 3;
        float w0 = wp[0], w1 = wp[1], w2 = wp[2];
        a0 += r[0] * w0 + r[1] * w1 + r[2] * w2;
        a1v += r[1] * w0 + r[2] * w1 + r[3] * w2;
        a2 += r[2] * w0 + r[3] * w1 + r[4] * w2;
        a3 += r[3] * w0 + r[4] * w1 + r[5] * w2;
      }
    }
  }
  float ps = a0 + a1v + a2 + a3;
  float pq = a0 * a0 + a1v * a1v + a2 * a2 + a3 * a3;
  __shared__ float sh[512];
  sh[threadIdx.x] = ps;
  sh[256 + threadIdx.x] = pq;
  __syncthreads();
  for (int s = 128; s > 0; s >>= 1) {
    if (threadIdx.x < (unsigned)s) {
      sh[threadIdx.x] += sh[threadIdx.x + s];
      sh[256 + threadIdx.x] += sh[256 + threadIdx.x + s];
    }
    __syncthreads();
  }
  if (threadIdx.x == 0) {
    atomicAdd(&sum[co], sh[0]);
    atomicAdd(&sq[co], sh[256]);
  }
}

__global__ __launch_bounds__(256) void final_conv_kernel(const u16* __restrict__ a1,
                                                         const void* __restrict__ x,
                                                         const float* __restrict__ w2f,
                                                         const float* __restrict__ wdf,
                                                         const float* __restrict__ S,
                                                         const int* __restrict__ flagp,
                                                         void* __restrict__ out) {
  const int bf = flagp[0];
  const int bid = blockIdx.x;
  const int co = bid & 31;
  const int rem = bid >> 5;
  const int d = rem / 20;
  const int p = (rem % 20) * 256 + threadIdx.x;
  const int y = p / 40;
  const int x0 = (p % 40) * 4;

  float a0 = 0.f, a1v = 0.f, a2 = 0.f, a3 = 0.f;
  for (int ci = 0; ci < COUT; ci++) {
#pragma unroll
    for (int kd = 0; kd < 3; kd++) {
      int dd = d - 1 + kd;
      if ((unsigned)dd >= (unsigned)D) continue;
      const int base = ci * DHW + dd * HW;
#pragma unroll
      for (int ky = 0; ky < 3; ky++) {
        int yy = y - 1 + ky;
        if ((unsigned)yy >= (unsigned)H) continue;
        const u16* row = a1 + base + yy * W;
        float r[6];
        {
          ushort4 v4 = *(const ushort4*)(row + x0);
          r[1] = bf2f(v4.x); r[2] = bf2f(v4.y); r[3] = bf2f(v4.z); r[4] = bf2f(v4.w);
        }
        r[0] = (x0 > 0) ? bf2f(row[x0 - 1]) : 0.f;
        r[5] = (x0 + 4 < W) ? bf2f(row[x0 + 4]) : 0.f;
        const float* wp = w2f + (((co * COUT + ci) * 3 + kd) * 3 + ky) * 3;
        float w0 = wp[0], w1 = wp[1], w2 = wp[2];
        a0 += r[0] * w0 + r[1] * w1 + r[2] * w2;
        a1v += r[1] * w0 + r[2] * w1 + r[3] * w2;
        a2 += r[2] * w0 + r[3] * w1 + r[4] * w2;
        a3 += r[3] * w0 + r[4] * w1 + r[5] * w2;
      }
    }
  }
  float b0 = 0.f, b1v = 0.f, b2v = 0.f, b3 = 0.f;
  for (int ci = 0; ci < CIN; ci++) {
#pragma unroll
    for (int kd = 0; kd < 3; kd++) {
      int dd = d - 1 + kd;
      if ((unsigned)dd >= (unsigned)D) continue;
      const int base = ci * DHW + dd * HW;
#pragma unroll
      for (int ky = 0; ky < 3; ky++) {
        int yy = y - 1 + ky;
        if ((unsigned)yy >= (unsigned)H) continue;
        const int rbase = base + yy * W;
        float r[6];
        if (bf) {
          ushort4 v4 = *(const ushort4*)((const u16*)x + rbase + x0);
          r[1] = bf2f(v4.x); r[2] = bf2f(v4.y); r[3] = bf2f(v4.z); r[4] = bf2f(v4.w);
        } else {
          float4 v4 = *(const float4*)((const float*)x + rbase + x0);
          r[1] = v4.x; r[2] = v4.y; r[3] = v4.z; r[4] = v4.w;
        }
        r[0] = (x0 > 0) ? ldin(x, rbase + x0 - 1, bf) : 0.f;
        r[5] = (x0 + 4 < W) ? ldin(x, rbase + x0 + 4, bf) : 0.f;
        const float* wp = wdf + (((co * CIN + ci) * 3 + kd) * 3 + ky) * 3;
        float w0 = wp[0], w1 = wp[1], w2 = wp[2];
        b0 += r[0] * w0 + r[1] * w1 + r[2] * w2;
        b1v += r[1] * w0 + r[2] * w1 + r[3] * w2;
        b2v += r[2] * w0 + r[3] * w1 + r[4] * w2;
        b3 += r[3] * w0 + r[4] * w1 + r[5] * w2;
      }
    }
  }

  float s2 = S[2176 + co], o2 = S[2208 + co];
  float sd = S[2240 + co], od = S[2272 + co];
  float r0 = fmaxf(a0 * s2 + o2 + b0 * sd + od, 0.f);
  float r1 = fmaxf(a1v * s2 + o2 + b1v * sd + od, 0.f);
  float r2 = fmaxf(a2 * s2 + o2 + b2v * sd + od, 0.f);
  float r3 = fmaxf(a3 * s2 + o2 + b3 * sd + od, 0.f);
  int oi = co * DHW + d * HW + y * W + x0;
  if (bf) {
    ushort4 st;
    st.x = f2bf(r0);
    st.y = f2bf(r1);
    st.z = f2bf(r2);
    st.w = f2bf(r3);
    *(ushort4*)((u16*)out + oi) = st;
  } else {
    float4 st;
    st.x = r0;
    st.y = r1;
    st.z = r2;
    st.w = r3;
    *(float4*)((float*)out + oi) = st;
  }
}

extern "C" void kernel_launch(void* const* d_in, const int* in_sizes, int n_in,
                              void* d_out, int out_size, void* d_ws, size_t ws_size,
                              hipStream_t stream) {
  const void* x = d_in[0];
  const void* f = d_in[1];

  char* ws = (char*)d_ws;
  float* S = (float*)ws;
  int* flag = (int*)ws + FLAG_SLOT;
  float* WF = (float*)(ws + WF_OFF);

  zero_kernel<<<16, 256, 0, stream>>>(S);
  sniff_kernel<<<1, 256, 0, stream>>>((const u16*)x, flag);

  // inputs: x,f,w_off,w_reg,g1,b1,w2,g2,b2,wd,gd,bd
  const int cvt_n[10] = {2592, 4608, 27648, 13824, 32, 32, 32, 32, 32, 32};
  const int cvt_off[10] = {WOFF_O, WREG_O, W2_O, WD_O, G1_O, B1_O, G2_O, B2_O, GD_O, BD_O};
  const int src_idx[10] = {2, 3, 6, 9, 4, 5, 7, 8, 10, 11};
  for (int k = 0; k < 10; k++) {
    cvt_kernel<<<(cvt_n[k] + 255) / 256, 256, 0, stream>>>(d_in[src_idx[k]], WF + cvt_off[k],
                                                           cvt_n[k], flag);
  }

  if (ws_size >= NEED_MFMA) {
    u16* a1ch = (u16*)(ws + A1_OFF);
    u16* xch = (u16*)(ws + XCH_OFF);
    u16* w2frag = (u16*)(ws + W2F_OFF);
    u16* wdfrag = (u16*)(ws + WDF_OFF);

    pack_frag_kernel<<<108, 256, 0, stream>>>(WF + W2_O, w2frag, 32);
    pack_frag_kernel<<<108, 256, 0, stream>>>(WF + WD_O, wdfrag, 16);
    xpose_kernel<<<DHW / 256, 256, 0, stream>>>(x, xch, flag);

    deform_ch_kernel<<<D * (HW / 256), 256, 0, stream>>>(x, f, WF + WOFF_O, WF + WREG_O, a1ch,
                                                         flag, S);
    bn1_scale_kernel<<<4, 256, 0, stream>>>(S, WF + G1_O, WF + B1_O);
    bn1_apply_ch_kernel<<<DHW / 256, 256, 0, stream>>>(a1ch, S);

    conv_mfma_stats_kernel<<<DHW / 256, 1024, 0, stream>>>(a1ch, xch, w2frag, wdfrag, S);
    bn3_final_kernel<<<1, 64, 0, stream>>>(S, WF + G2_O, WF + B2_O, WF + GD_O, WF + BD_O);
    conv_mfma_final_kernel<<<DHW / 64, 256, 0, stream>>>(a1ch, xch, w2frag, wdfrag, S, flag,
                                                         d_out);
  } else {
    u16* a1 = (u16*)(ws + A1_OFF);
    deform_kernel<<<D * (HW / 256), 256, 0, stream>>>(x, f, WF + WOFF_O, WF + WREG_O, a1, flag);
    bn1_stats_kernel<<<COUT * D, 256, 0, stream>>>(a1, WF + G1_O, WF + B1_O, S);
    bn1_apply_kernel<<<NOUT / 1024, 256, 0, stream>>>(a1, S);
    conv_stats_kernel<<<COUT * D * 20, 256, 0, stream>>>(a1, WF + W2_O, COUT, 1, flag, S + 2048,
                                                         S + 2080);
    conv_stats_kernel<<<COUT * D * 20, 256, 0, stream>>>(x, WF + WD_O, CIN, 0, flag, S + 2112,
                                                         S + 2144);
    bn3_final_kernel<<<1, 64, 0, stream>>>(S, WF + G2_O, WF + B2_O, WF + GD_O, WF + BD_O);
    final_conv_kernel<<<COUT * D * 20, 256, 0, stream>>>(a1, x, WF + W2_O, WF + WD_O, S, flag,
                                                         d_out);
  }
}